// Round 1
// baseline (14558.601 us; speedup 1.0000x reference)
//
#include <hip/hip_runtime.h>
#include <hip/hip_cooperative_groups.h>

namespace cg = cooperative_groups;

constexpr int B_  = 128;
constexpr int T_  = 152;
constexpr int I_  = 75;
constexpr int H_  = 256;
constexpr int L_  = 16;
constexpr int C_  = 625;
constexpr int G4  = 1024;          // 4*H
constexpr float EPS_ = 1e-5f;
constexpr int WPL = 16;            // workgroups per layer
constexpr int NBLK = L_ * WPL;     // 256 workgroups
constexpr int ND  = T_ + L_ - 1;   // 167 diagonals

// ---------------------------------------------------------------------------
// Layer-0 input projection + BN (over batch, per (t, col)), all timesteps.
// Grid: (16 col-slices of 64, T). Block: 256. Tile: 128(batch) x 64(cols), K=75.
// ---------------------------------------------------------------------------
__global__ void __launch_bounds__(256)
bnwi0_kernel(const float* __restrict__ seq, const float* __restrict__ Wih0,
             const float* __restrict__ g_ih, const float* __restrict__ b_ih,
             float* __restrict__ outw) {
    __shared__ float xsl[B_][I_];     // 128 x 75 (odd stride: conflict-benign)
    __shared__ float wsl[I_][64];     // 75 x 64  (reused as reduction scratch)
    __shared__ float mvM[64];
    __shared__ float mvI[64];

    const int t   = blockIdx.y;
    const int n0  = blockIdx.x * 64;
    const int tid = threadIdx.x;
    const int tx  = tid & 15;         // col group: cols 4tx..4tx+3
    const int ty  = tid >> 4;         // batch rows ty*8..ty*8+7

    for (int idx = tid; idx < B_ * I_; idx += 256) {
        int bb = idx / I_, k = idx % I_;
        xsl[bb][k] = seq[((size_t)bb * T_ + t) * I_ + k];
    }
    for (int idx = tid; idx < I_ * 64; idx += 256) {
        int k = idx >> 6, c = idx & 63;
        wsl[k][c] = Wih0[(size_t)k * G4 + n0 + c];
    }
    __syncthreads();

    float acc[8][4];
#pragma unroll
    for (int i = 0; i < 8; ++i)
#pragma unroll
        for (int c = 0; c < 4; ++c) acc[i][c] = 0.f;

    for (int k = 0; k < I_; ++k) {
        float w0 = wsl[k][4 * tx + 0];
        float w1 = wsl[k][4 * tx + 1];
        float w2 = wsl[k][4 * tx + 2];
        float w3 = wsl[k][4 * tx + 3];
#pragma unroll
        for (int i = 0; i < 8; ++i) {
            float xv = xsl[ty * 8 + i][k];
            acc[i][0] += xv * w0;
            acc[i][1] += xv * w1;
            acc[i][2] += xv * w2;
            acc[i][3] += xv * w3;
        }
    }
    __syncthreads();   // wsl reused as reduction scratch below

    float (*redS)[16] = (float (*)[16])(&wsl[0][0]);
    float (*redQ)[16] = (float (*)[16])(&wsl[0][0] + 1024);

#pragma unroll
    for (int c = 0; c < 4; ++c) {
        float s = 0.f, q = 0.f;
#pragma unroll
        for (int i = 0; i < 8; ++i) { float a = acc[i][c]; s += a; q += a * a; }
        redS[4 * tx + c][ty] = s;
        redQ[4 * tx + c][ty] = q;
    }
    __syncthreads();
    if (tid < 64) {
        float s = 0.f, q = 0.f;
#pragma unroll
        for (int j = 0; j < 16; ++j) { s += redS[tid][j]; q += redQ[tid][j]; }
        float m = s * (1.0f / B_);
        float v = q * (1.0f / B_) - m * m;
        mvM[tid] = m;
        mvI[tid] = rsqrtf(fmaxf(v, 0.f) + EPS_);
    }
    __syncthreads();

#pragma unroll
    for (int i = 0; i < 8; ++i) {
        float vals[4];
#pragma unroll
        for (int c = 0; c < 4; ++c) {
            int col = 4 * tx + c;
            vals[c] = (acc[i][c] - mvM[col]) * mvI[col] * g_ih[n0 + col] + b_ih[n0 + col];
        }
        float4 o;
        o.x = vals[0]; o.y = vals[1]; o.z = vals[2]; o.w = vals[3];
        *(float4*)&outw[((size_t)t * B_ + ty * 8 + i) * G4 + n0 + 4 * tx] = o;
    }
}

// ---------------------------------------------------------------------------
// Wavefront cell helpers
// ---------------------------------------------------------------------------
__device__ __forceinline__ void gemm_128x64(
    const float* __restrict__ X,      // (128, 256) row-major (global)
    const float* __restrict__ Wmat,   // (256, 1024) row-major (global)
    int j0, int tid, int tx, int ty, int brow,
    float (*xs)[68], float (*wsT)[68],
    float acc[8][4]) {
#pragma unroll
    for (int i = 0; i < 8; ++i)
#pragma unroll
        for (int g = 0; g < 4; ++g) acc[i][g] = 0.f;

    for (int k0 = 0; k0 < H_; k0 += 64) {
        __syncthreads();
        // stage X[:, k0:k0+64] -> xs (coalesced float4)
#pragma unroll
        for (int r = 0; r < 8; ++r) {
            int idx = r * 256 + tid;
            int bb  = idx >> 4;
            int k4  = (idx & 15) << 2;
            *(float4*)&xs[bb][k4] = *(const float4*)&X[(size_t)bb * H_ + k0 + k4];
        }
        // stage W cols {g*256 + j0 .. +16} transposed -> wsT[c][kk]
#pragma unroll
        for (int r = 0; r < 16; ++r) {
            int idx = r * 256 + tid;
            int cc  = idx & 15;
            int kk  = (idx >> 4) & 63;
            int gg  = idx >> 10;
            wsT[gg * 16 + cc][kk] = Wmat[(size_t)(k0 + kk) * G4 + gg * H_ + j0 + cc];
        }
        __syncthreads();
#pragma unroll 2
        for (int kk = 0; kk < 64; kk += 4) {
            float4 wv0 = *(const float4*)&wsT[tx][kk];
            float4 wv1 = *(const float4*)&wsT[16 + tx][kk];
            float4 wv2 = *(const float4*)&wsT[32 + tx][kk];
            float4 wv3 = *(const float4*)&wsT[48 + tx][kk];
#pragma unroll
            for (int i = 0; i < 8; ++i) {
                float4 xv = *(const float4*)&xs[brow + i][kk];
                acc[i][0] += xv.x * wv0.x + xv.y * wv0.y + xv.z * wv0.z + xv.w * wv0.w;
                acc[i][1] += xv.x * wv1.x + xv.y * wv1.y + xv.z * wv1.z + xv.w * wv1.w;
                acc[i][2] += xv.x * wv2.x + xv.y * wv2.y + xv.z * wv2.z + xv.w * wv2.w;
                acc[i][3] += xv.x * wv3.x + xv.y * wv3.y + xv.z * wv3.z + xv.w * wv3.w;
            }
        }
    }
}

__device__ __forceinline__ void bn_stats_64(
    const float acc[8][4], int tx, int ty, int tid,
    float (*redS)[16][16], float (*redQ)[16][16],
    float (*mvM)[16], float (*mvI)[16]) {
#pragma unroll
    for (int g = 0; g < 4; ++g) {
        float s = 0.f, q = 0.f;
#pragma unroll
        for (int i = 0; i < 8; ++i) { float a = acc[i][g]; s += a; q += a * a; }
        redS[g][tx][ty] = s;
        redQ[g][tx][ty] = q;
    }
    __syncthreads();
    if (tid < 64) {
        int g = tid >> 4, c = tid & 15;
        float s = 0.f, q = 0.f;
#pragma unroll
        for (int j = 0; j < 16; ++j) { s += redS[g][c][j]; q += redQ[g][c][j]; }
        float m = s * (1.0f / B_);
        float v = q * (1.0f / B_) - m * m;
        mvM[g][c] = m;
        mvI[g][c] = rsqrtf(fmaxf(v, 0.f) + EPS_);
    }
    __syncthreads();
}

// ---------------------------------------------------------------------------
// Wavefront kernel: 256 WGs = 16 layers x 16 col-groups, cooperative.
// Each WG owns hidden units [gq*16, gq*16+16) of its layer; c in registers.
// ---------------------------------------------------------------------------
__global__ void __launch_bounds__(256, 1)
wave_kernel(const float* __restrict__ Wih, const float* __restrict__ Whh,
            const float* __restrict__ bias,
            const float* __restrict__ g_ih, const float* __restrict__ b_ih,
            const float* __restrict__ g_hh, const float* __restrict__ b_hh,
            const float* __restrict__ g_c,  const float* __restrict__ b_c,
            const float* __restrict__ bnwi0, float* __restrict__ Hbuf) {
    cg::grid_group grid = cg::this_grid();

    __shared__ alignas(16) float xs[B_][68];
    __shared__ alignas(16) float wsT[64][68];
    __shared__ float redS[4][16][16];
    __shared__ float redQ[4][16][16];
    __shared__ float mvM[4][16];
    __shared__ float mvI[4][16];
    __shared__ float cms[16];
    __shared__ float cis[16];

    const int l    = blockIdx.x >> 4;
    const int gq   = blockIdx.x & 15;
    const int j0   = gq * 16;
    const int tid  = threadIdx.x;
    const int tx   = tid & 15;
    const int ty   = tid >> 4;
    const int jc   = j0 + tx;          // hidden column owned by this thread
    const int brow = ty * 8;           // batch rows brow..brow+7

    // per-column constants (f,i,o,g blocks)
    float gihv[4], bihv[4], ghhv[4], bhhv[4], bsv[4];
#pragma unroll
    for (int g = 0; g < 4; ++g) {
        int col = l * G4 + g * H_ + jc;
        gihv[g] = g_ih[col];
        bihv[g] = b_ih[col];
        ghhv[g] = g_hh[col];
        bhhv[g] = b_hh[col];
        bsv[g]  = bias[col];
    }
    const float gcv = g_c[l * H_ + jc];
    const float bcv = b_c[l * H_ + jc];

    const float* Wi = (l > 0) ? (Wih + (size_t)(l - 1) * H_ * G4) : Wih;
    const float* Wh = Whh + (size_t)l * H_ * G4;

    float creg[8];
#pragma unroll
    for (int i = 0; i < 8; ++i) creg[i] = 0.f;

    for (int d = 0; d < ND; ++d) {
        const int t = d - l;
        if (t >= 0 && t < T_) {
            const int pr = (d + 1) & 1;   // parity written at diagonal d-1
            const int pw = d & 1;

            float bnwi[8][4];
            float acc[8][4];

            // ---- input-projection gates (BN'd) ----
            if (l == 0) {
#pragma unroll
                for (int i = 0; i < 8; ++i) {
                    const float* p = bnwi0 + (size_t)(t * B_ + brow + i) * G4 + jc;
#pragma unroll
                    for (int g = 0; g < 4; ++g) bnwi[i][g] = p[g * H_];
                }
            } else {
                const float* X = Hbuf + (size_t)((l - 1) * 2 + pr) * B_ * H_;
                gemm_128x64(X, Wi, j0, tid, tx, ty, brow, xs, wsT, acc);
                bn_stats_64(acc, tx, ty, tid, redS, redQ, mvM, mvI);
#pragma unroll
                for (int g = 0; g < 4; ++g) {
                    float m = mvM[g][tx], is = mvI[g][tx];
#pragma unroll
                    for (int i = 0; i < 8; ++i)
                        bnwi[i][g] = (acc[i][g] - m) * is * gihv[g] + bihv[g];
                }
            }

            // ---- recurrent gates ----
            const float* Hp = Hbuf + (size_t)(l * 2 + pr) * B_ * H_;
            gemm_128x64(Hp, Wh, j0, tid, tx, ty, brow, xs, wsT, acc);
            bn_stats_64(acc, tx, ty, tid, redS, redQ, mvM, mvI);

            float osv[8];
#pragma unroll
            for (int i = 0; i < 8; ++i) {
                float sg[4];
#pragma unroll
                for (int g = 0; g < 4; ++g)
                    sg[g] = (acc[i][g] - mvM[g][tx]) * mvI[g][tx] * ghhv[g] + bhhv[g]
                            + bnwi[i][g] + bsv[g];
                float fg = 1.f / (1.f + expf(-sg[0]));
                float ig = 1.f / (1.f + expf(-sg[1]));
                osv[i]   = sg[2];
                creg[i]  = fg * creg[i] + ig * tanhf(sg[3]);
            }

            // ---- BN over c (per hidden column, over batch) ----
            {
                float s = 0.f, q = 0.f;
#pragma unroll
                for (int i = 0; i < 8; ++i) { s += creg[i]; q += creg[i] * creg[i]; }
                redS[0][tx][ty] = s;
                redQ[0][tx][ty] = q;
            }
            __syncthreads();
            if (tid < 16) {
                float s = 0.f, q = 0.f;
#pragma unroll
                for (int j = 0; j < 16; ++j) { s += redS[0][tid][j]; q += redQ[0][tid][j]; }
                float m = s * (1.0f / B_);
                float v = q * (1.0f / B_) - m * m;
                cms[tid] = m;
                cis[tid] = rsqrtf(fmaxf(v, 0.f) + EPS_);
            }
            __syncthreads();
            {
                const float m = cms[tx], is = cis[tx];
                float* Hw = Hbuf + (size_t)(l * 2 + pw) * B_ * H_;
#pragma unroll
                for (int i = 0; i < 8; ++i) {
                    float og = 1.f / (1.f + expf(-osv[i]));
                    float hv = og * tanhf((creg[i] - m) * is * gcv + bcv);
                    Hw[(size_t)(brow + i) * H_ + jc] = hv;
                }
            }
        }
        grid.sync();
    }
}

// ---------------------------------------------------------------------------
// Final linear + softmax: one WG per batch row.
// ---------------------------------------------------------------------------
__global__ void __launch_bounds__(256)
final_kernel(const float* __restrict__ Hbuf, const float* __restrict__ Wlin,
             const float* __restrict__ blin, float* __restrict__ out) {
    const int b   = blockIdx.x;
    const int tid = threadIdx.x;
    __shared__ float hs[H_];
    __shared__ float rbuf[256];
    constexpr int lastPar = (ND - 1) & 1;  // parity of h written at d = 166

    hs[tid] = Hbuf[(size_t)((L_ - 1) * 2 + lastPar) * B_ * H_ + (size_t)b * H_ + tid];
    __syncthreads();

    float lg[3];
#pragma unroll
    for (int r = 0; r < 3; ++r) {
        int cls = tid + r * 256;
        float a = -1e30f;
        if (cls < C_) {
            a = blin[cls];
            for (int j = 0; j < H_; ++j) a += hs[j] * Wlin[(size_t)j * C_ + cls];
        }
        lg[r] = a;
    }

    float mx = fmaxf(fmaxf(lg[0], lg[1]), lg[2]);
    rbuf[tid] = mx;
    __syncthreads();
    for (int s = 128; s > 0; s >>= 1) {
        if (tid < s) rbuf[tid] = fmaxf(rbuf[tid], rbuf[tid + s]);
        __syncthreads();
    }
    mx = rbuf[0];
    __syncthreads();

    float ev[3];
    float es = 0.f;
#pragma unroll
    for (int r = 0; r < 3; ++r) {
        int cls = tid + r * 256;
        if (cls < C_) { ev[r] = expf(lg[r] - mx); es += ev[r]; }
        else ev[r] = 0.f;
    }
    rbuf[tid] = es;
    __syncthreads();
    for (int s = 128; s > 0; s >>= 1) {
        if (tid < s) rbuf[tid] += rbuf[tid + s];
        __syncthreads();
    }
    const float inv = 1.f / rbuf[0];
#pragma unroll
    for (int r = 0; r < 3; ++r) {
        int cls = tid + r * 256;
        if (cls < C_) out[(size_t)b * C_ + cls] = ev[r] * inv;
    }
}

// ---------------------------------------------------------------------------
extern "C" void kernel_launch(void* const* d_in, const int* in_sizes, int n_in,
                              void* d_out, int out_size, void* d_ws, size_t ws_size,
                              hipStream_t stream) {
    const float* seq  = (const float*)d_in[0];
    const float* Wih0 = (const float*)d_in[1];
    const float* Wih  = (const float*)d_in[2];
    const float* Whh  = (const float*)d_in[3];
    const float* bias = (const float*)d_in[4];
    const float* gih  = (const float*)d_in[5];
    const float* bih  = (const float*)d_in[6];
    const float* ghh  = (const float*)d_in[7];
    const float* bhh  = (const float*)d_in[8];
    const float* gc   = (const float*)d_in[9];
    const float* bc   = (const float*)d_in[10];
    const float* Wlin = (const float*)d_in[11];
    const float* blin = (const float*)d_in[12];
    float* out = (float*)d_out;

    float* bnwi0 = (float*)d_ws;                         // T*B*4H floats (~80 MB)
    float* Hbuf  = bnwi0 + (size_t)T_ * B_ * G4;         // L*2*B*H floats (4 MB)

    hipMemsetAsync(Hbuf, 0, (size_t)L_ * 2 * B_ * H_ * sizeof(float), stream);

    bnwi0_kernel<<<dim3(G4 / 64, T_), 256, 0, stream>>>(seq, Wih0, gih, bih, bnwi0);

    {
        void* args[] = { (void*)&Wih, (void*)&Whh, (void*)&bias,
                         (void*)&gih, (void*)&bih, (void*)&ghh, (void*)&bhh,
                         (void*)&gc,  (void*)&bc,  (void*)&bnwi0, (void*)&Hbuf };
        hipError_t e = hipLaunchCooperativeKernel((void*)wave_kernel, dim3(NBLK),
                                                  dim3(256), args, 0, stream);
        if (e != hipSuccess) {
            // fallback: 256 blocks <= 256 CUs -> co-resident in practice
            wave_kernel<<<dim3(NBLK), 256, 0, stream>>>(Wih, Whh, bias, gih, bih,
                                                        ghh, bhh, gc, bc, bnwi0, Hbuf);
        }
    }

    final_kernel<<<B_, 256, 0, stream>>>(Hbuf, Wlin, blin, out);
}

// Round 4
// 7217.351 us; speedup vs baseline: 2.0172x; 2.0172x over previous
//
#include <hip/hip_runtime.h>

typedef short s16x8 __attribute__((ext_vector_type(8)));
typedef float f32x4 __attribute__((ext_vector_type(4)));

constexpr int B_  = 128;
constexpr int T_  = 152;
constexpr int I_  = 75;
constexpr int H_  = 256;
constexpr int L_  = 16;
constexpr int C_  = 625;
constexpr int G4  = 1024;          // 4*H
constexpr float EPS_ = 1e-5f;
constexpr int NBLK = 256;          // 16 layers x 16 col-groups
constexpr int ND  = T_ + L_ - 1;   // 167 diagonals
constexpr int NMAT = 31;           // 15 W_ih (layers 1..15) + 16 W_hh
constexpr size_t MATSZ = (size_t)G4 * H_;   // 262144 elems per matrix

__device__ __forceinline__ f32x4 mfma16(s16x8 a, s16x8 b, f32x4 c) {
    return __builtin_amdgcn_mfma_f32_16x16x32_bf16(a, b, c, 0, 0, 0);
}

__device__ __forceinline__ float sigm(float x) { return 1.f / (1.f + expf(-x)); }

__device__ __forceinline__ short f2bf(float x) {
    __bf16 h = (__bf16)x;
    return __builtin_bit_cast(short, h);
}
__device__ __forceinline__ float bf2f(short s) {
    __bf16 h = __builtin_bit_cast(__bf16, s);
    return (float)h;
}

// ---------------------------------------------------------------------------
// Manual grid barrier: per-diagonal monotonic counter (no reset needed).
// flags must be zeroed before launch. Safe under plain launch because all 256
// blocks are co-resident (1 block/CU).
// ---------------------------------------------------------------------------
__device__ __forceinline__ void grid_barrier(unsigned* flag) {
    __syncthreads();
    if (threadIdx.x == 0) {
        __threadfence();
        __hip_atomic_fetch_add(flag, 1u, __ATOMIC_ACQ_REL, __HIP_MEMORY_SCOPE_AGENT);
        while (__hip_atomic_load(flag, __ATOMIC_ACQUIRE, __HIP_MEMORY_SCOPE_AGENT)
               < (unsigned)NBLK) {
            __builtin_amdgcn_s_sleep(2);
        }
    }
    __syncthreads();
}

// ---------------------------------------------------------------------------
// Prep: transpose W (k,4H) -> (4H,k) and split fp32 into bf16 hi/lo planes.
// Grid: (16 n-tiles, 4 k-tiles, 31 mats). Block 256.
// ---------------------------------------------------------------------------
__global__ void __launch_bounds__(256)
prep_kernel(const float* __restrict__ Wih, const float* __restrict__ Whh,
            short* __restrict__ Wth, short* __restrict__ Wtl) {
    __shared__ float tile[64][65];
    const int mat = blockIdx.z;
    const int n0  = blockIdx.x * 64;
    const int k0  = blockIdx.y * 64;
    const int tid = threadIdx.x;
    const float* src = (mat < 15) ? (Wih + (size_t)mat * MATSZ)
                                  : (Whh + (size_t)(mat - 15) * MATSZ);
#pragma unroll
    for (int r = 0; r < 16; ++r) {
        int idx = r * 256 + tid;
        int kk = idx >> 6, nn = idx & 63;
        tile[kk][nn] = src[(size_t)(k0 + kk) * G4 + n0 + nn];
    }
    __syncthreads();
#pragma unroll
    for (int r = 0; r < 16; ++r) {
        int idx = r * 256 + tid;
        int nn = idx >> 6, kk = idx & 63;
        float w = tile[kk][nn];
        short hi = f2bf(w);
        short lo = f2bf(w - bf2f(hi));
        size_t o = ((size_t)mat * G4 + n0 + nn) * H_ + k0 + kk;
        Wth[o] = hi;
        Wtl[o] = lo;
    }
}

// ---------------------------------------------------------------------------
// MFMA GEMM: out 128 x 64 (4 gate stripes of 16), K = 256, hi/lo bf16 4-term.
// X: [128][256] bf16(short) planes. W: [1024 rows = gate cols][256] planes.
// ---------------------------------------------------------------------------
__device__ __forceinline__ void gemm_mfma(
    const short* __restrict__ Xh, const short* __restrict__ Xl,
    const short* __restrict__ Wh, const short* __restrict__ Wl,
    int j0, int tid,
    short (*xsh)[72], short (*xsl)[72],
    short (*wsh)[72], short (*wsl)[72],
    f32x4 acc[2][4]) {
    const int lane = tid & 63;
    const int wv   = tid >> 6;
    const int quad = lane >> 4;
    const int lcol = lane & 15;

#pragma unroll
    for (int mt = 0; mt < 2; ++mt)
#pragma unroll
        for (int g = 0; g < 4; ++g) acc[mt][g] = (f32x4){0.f, 0.f, 0.f, 0.f};

    for (int k0 = 0; k0 < H_; k0 += 64) {
        __syncthreads();
        // stage X slice (both planes): 128 rows x 64 k
#pragma unroll
        for (int r = 0; r < 4; ++r) {
            int idx = (r << 8) + tid;
            int row = idx >> 3;
            int kg  = (idx & 7) << 3;
            *(s16x8*)&xsh[row][kg] = *(const s16x8*)&Xh[row * H_ + k0 + kg];
            *(s16x8*)&xsl[row][kg] = *(const s16x8*)&Xl[row * H_ + k0 + kg];
        }
        // stage W slice: 64 rows (4 gates x 16 cols) x 64 k
        {
            int row = tid >> 2;               // 0..63
            int g = row >> 4, c = row & 15;
            int kg = (tid & 3) << 4;          // 0,16,32,48
            size_t go = ((size_t)(g * H_ + j0 + c)) * H_ + k0 + kg;
            *(s16x8*)&wsh[row][kg]     = *(const s16x8*)&Wh[go];
            *(s16x8*)&wsh[row][kg + 8] = *(const s16x8*)&Wh[go + 8];
            *(s16x8*)&wsl[row][kg]     = *(const s16x8*)&Wl[go];
            *(s16x8*)&wsl[row][kg + 8] = *(const s16x8*)&Wl[go + 8];
        }
        __syncthreads();
#pragma unroll
        for (int ks = 0; ks < 2; ++ks) {
            int kk = (ks << 5) + (quad << 3);
            s16x8 ah[2], al[2], bh[4], bl[4];
#pragma unroll
            for (int mt = 0; mt < 2; ++mt) {
                ah[mt] = *(const s16x8*)&xsh[wv * 32 + mt * 16 + lcol][kk];
                al[mt] = *(const s16x8*)&xsl[wv * 32 + mt * 16 + lcol][kk];
            }
#pragma unroll
            for (int g = 0; g < 4; ++g) {
                bh[g] = *(const s16x8*)&wsh[g * 16 + lcol][kk];
                bl[g] = *(const s16x8*)&wsl[g * 16 + lcol][kk];
            }
#pragma unroll
            for (int mt = 0; mt < 2; ++mt)
#pragma unroll
                for (int g = 0; g < 4; ++g) {
                    acc[mt][g] = mfma16(ah[mt], bh[g], acc[mt][g]);
                    acc[mt][g] = mfma16(al[mt], bh[g], acc[mt][g]);
                    acc[mt][g] = mfma16(ah[mt], bl[g], acc[mt][g]);
                    acc[mt][g] = mfma16(al[mt], bl[g], acc[mt][g]);
                }
        }
    }
}

// BN stats over batch (128 rows) per (gate, col). acc in C-layout.
__device__ __forceinline__ void bn_stats(
    const f32x4 acc[2][4], int tid,
    float (*redS)[4][16], float (*redQ)[4][16],
    float (*mvM)[16], float (*mvI)[16]) {
    const int lane = tid & 63;
    const int wv   = tid >> 6;
    const int lcol = lane & 15;
#pragma unroll
    for (int g = 0; g < 4; ++g) {
        float s = 0.f, q = 0.f;
#pragma unroll
        for (int mt = 0; mt < 2; ++mt)
#pragma unroll
            for (int r = 0; r < 4; ++r) { float a = acc[mt][g][r]; s += a; q += a * a; }
        s += __shfl_xor(s, 16); s += __shfl_xor(s, 32);
        q += __shfl_xor(q, 16); q += __shfl_xor(q, 32);
        if (lane < 16) { redS[g][wv][lcol] = s; redQ[g][wv][lcol] = q; }
    }
    __syncthreads();
    if (tid < 64) {
        int g = tid >> 4, c = tid & 15;
        float s = redS[g][0][c] + redS[g][1][c] + redS[g][2][c] + redS[g][3][c];
        float q = redQ[g][0][c] + redQ[g][1][c] + redQ[g][2][c] + redQ[g][3][c];
        float m = s * (1.0f / B_);
        float v = q * (1.0f / B_) - m * m;
        mvM[g][c] = m;
        mvI[g][c] = rsqrtf(fmaxf(v, 0.f) + EPS_);
    }
    __syncthreads();
}

// ---------------------------------------------------------------------------
// Wavefront kernel: 256 WGs, plain launch + manual flag barrier.
// LDS arena (phase-shared):
//   phase A (layer-0 proj): xs0 f32[128][77] @0, w0s f32[75][68] @39424,
//                           proj f32[128][68] @0 (after sync)
//   phase B (MFMA GEMM):    xsh/xsl s16[128][72] @0/@18432,
//                           wsh/wsl s16[64][72]  @36864/@46080
// ---------------------------------------------------------------------------
__global__ void __launch_bounds__(256, 1)
wave_kernel(const short* __restrict__ Wth, const short* __restrict__ Wtl,
            const float* __restrict__ Wih0, const float* __restrict__ seq,
            const float* __restrict__ bias,
            const float* __restrict__ g_ih, const float* __restrict__ b_ih,
            const float* __restrict__ g_hh, const float* __restrict__ b_hh,
            const float* __restrict__ g_c,  const float* __restrict__ b_c,
            short* __restrict__ Hh, short* __restrict__ Hl,
            unsigned* __restrict__ flags) {
    __shared__ alignas(16) char arena[59840];
    __shared__ float redS[4][4][16];
    __shared__ float redQ[4][4][16];
    __shared__ float mvM[4][16], mvI[4][16];
    __shared__ float cms[16], cis[16];

    short (*xsh)[72] = (short(*)[72])(arena);
    short (*xsl)[72] = (short(*)[72])(arena + 18432);
    short (*wsh)[72] = (short(*)[72])(arena + 36864);
    short (*wsl)[72] = (short(*)[72])(arena + 46080);
    float* xs0  = (float*)arena;                 // [128][77]
    float* w0s  = (float*)(arena + 39424);       // [75][68]
    float* proj = (float*)arena;                 // [128][68]

    const int b   = blockIdx.x;
    const int l   = ((b & 7) << 1) | ((b >> 3) & 1);  // XCD b%8 hosts layers 2x,2x+1
    const int gq  = b >> 4;
    const int j0  = gq * 16;
    const int tid = threadIdx.x;
    const int lane = tid & 63;
    const int wv   = tid >> 6;
    const int quad = lane >> 4;
    const int lcol = lane & 15;
    const int jc   = j0 + lcol;
    const int tx   = tid & 15;
    const int ty4  = tid >> 4;

    float gihv[4], bihv[4], ghhv[4], bhhv[4], bsv[4];
#pragma unroll
    for (int g = 0; g < 4; ++g) {
        int col = l * G4 + g * H_ + jc;
        gihv[g] = g_ih[col];
        bihv[g] = b_ih[col];
        ghhv[g] = g_hh[col];
        bhhv[g] = b_hh[col];
        bsv[g]  = bias[col];
    }
    const float gcv = g_c[l * H_ + jc];
    const float bcv = b_c[l * H_ + jc];

    const short* Wi_h = (l > 0) ? (Wth + (size_t)(l - 1) * MATSZ) : Wth;
    const short* Wi_l = (l > 0) ? (Wtl + (size_t)(l - 1) * MATSZ) : Wtl;
    const short* Wr_h = Wth + (size_t)(15 + l) * MATSZ;
    const short* Wr_l = Wtl + (size_t)(15 + l) * MATSZ;

    f32x4 creg[2];
    creg[0] = (f32x4){0.f, 0.f, 0.f, 0.f};
    creg[1] = (f32x4){0.f, 0.f, 0.f, 0.f};

    for (int d = 0; d < ND; ++d) {
        const int t = d - l;
        if (t >= 0 && t < T_) {
            const int pr = (d + 1) & 1;
            const int pw = d & 1;

            f32x4 bnwi[2][4];
            f32x4 acc[2][4];

            if (l == 0) {
                // ---- inline fp32 input projection x_t @ W0 (K=75) ----
                for (int idx = tid; idx < B_ * I_; idx += 256) {
                    int row = idx / I_;
                    int k   = idx - row * I_;
                    xs0[row * 77 + k] = seq[(size_t)row * (T_ * I_) + t * I_ + k];
                }
                for (int idx = tid; idx < 64 * I_; idx += 256) {
                    int k  = idx >> 6;
                    int cc = idx & 63;
                    w0s[k * 68 + cc] = Wih0[(size_t)k * G4 + (cc >> 4) * H_ + j0 + (cc & 15)];
                }
                __syncthreads();
                float pacc[8][4];
#pragma unroll
                for (int i = 0; i < 8; ++i)
#pragma unroll
                    for (int c = 0; c < 4; ++c) pacc[i][c] = 0.f;
                for (int k = 0; k < I_; ++k) {
                    float4 wvv = *(const float4*)&w0s[k * 68 + 4 * tx];
#pragma unroll
                    for (int i = 0; i < 8; ++i) {
                        float xv = xs0[(ty4 + 16 * i) * 77 + k];
                        pacc[i][0] += xv * wvv.x;
                        pacc[i][1] += xv * wvv.y;
                        pacc[i][2] += xv * wvv.z;
                        pacc[i][3] += xv * wvv.w;
                    }
                }
                __syncthreads();
#pragma unroll
                for (int i = 0; i < 8; ++i) {
                    float4 o;
                    o.x = pacc[i][0]; o.y = pacc[i][1]; o.z = pacc[i][2]; o.w = pacc[i][3];
                    *(float4*)&proj[(ty4 + 16 * i) * 68 + 4 * tx] = o;
                }
                __syncthreads();
#pragma unroll
                for (int mt = 0; mt < 2; ++mt)
#pragma unroll
                    for (int g = 0; g < 4; ++g)
#pragma unroll
                        for (int r = 0; r < 4; ++r)
                            acc[mt][g][r] = proj[(wv * 32 + mt * 16 + quad * 4 + r) * 68
                                                 + g * 16 + lcol];
                bn_stats(acc, tid, redS, redQ, mvM, mvI);
#pragma unroll
                for (int g = 0; g < 4; ++g) {
                    float m = mvM[g][lcol], is = mvI[g][lcol];
#pragma unroll
                    for (int mt = 0; mt < 2; ++mt)
#pragma unroll
                        for (int r = 0; r < 4; ++r)
                            bnwi[mt][g][r] = (acc[mt][g][r] - m) * is * gihv[g] + bihv[g];
                }
            } else {
                const short* Xh = Hh + (size_t)((l - 1) * 2 + pr) * B_ * H_;
                const short* Xl = Hl + (size_t)((l - 1) * 2 + pr) * B_ * H_;
                gemm_mfma(Xh, Xl, Wi_h, Wi_l, j0, tid, xsh, xsl, wsh, wsl, acc);
                bn_stats(acc, tid, redS, redQ, mvM, mvI);
#pragma unroll
                for (int g = 0; g < 4; ++g) {
                    float m = mvM[g][lcol], is = mvI[g][lcol];
#pragma unroll
                    for (int mt = 0; mt < 2; ++mt)
#pragma unroll
                        for (int r = 0; r < 4; ++r)
                            bnwi[mt][g][r] = (acc[mt][g][r] - m) * is * gihv[g] + bihv[g];
                }
            }

            {
                const short* Xh = Hh + (size_t)(l * 2 + pr) * B_ * H_;
                const short* Xl = Hl + (size_t)(l * 2 + pr) * B_ * H_;
                gemm_mfma(Xh, Xl, Wr_h, Wr_l, j0, tid, xsh, xsl, wsh, wsl, acc);
            }
            bn_stats(acc, tid, redS, redQ, mvM, mvI);

            f32x4 osv[2];
#pragma unroll
            for (int mt = 0; mt < 2; ++mt) {
#pragma unroll
                for (int r = 0; r < 4; ++r) {
                    float sf = (acc[mt][0][r] - mvM[0][lcol]) * mvI[0][lcol] * ghhv[0] + bhhv[0] + bnwi[mt][0][r] + bsv[0];
                    float si = (acc[mt][1][r] - mvM[1][lcol]) * mvI[1][lcol] * ghhv[1] + bhhv[1] + bnwi[mt][1][r] + bsv[1];
                    float so = (acc[mt][2][r] - mvM[2][lcol]) * mvI[2][lcol] * ghhv[2] + bhhv[2] + bnwi[mt][2][r] + bsv[2];
                    float sg = (acc[mt][3][r] - mvM[3][lcol]) * mvI[3][lcol] * ghhv[3] + bhhv[3] + bnwi[mt][3][r] + bsv[3];
                    creg[mt][r] = sigm(sf) * creg[mt][r] + sigm(si) * tanhf(sg);
                    osv[mt][r]  = so;
                }
            }

            // BN over c
            {
                float s = 0.f, q = 0.f;
#pragma unroll
                for (int mt = 0; mt < 2; ++mt)
#pragma unroll
                    for (int r = 0; r < 4; ++r) { float a = creg[mt][r]; s += a; q += a * a; }
                s += __shfl_xor(s, 16); s += __shfl_xor(s, 32);
                q += __shfl_xor(q, 16); q += __shfl_xor(q, 32);
                if (lane < 16) { redS[0][wv][lcol] = s; redQ[0][wv][lcol] = q; }
            }
            __syncthreads();
            if (tid < 16) {
                float s = redS[0][0][tid] + redS[0][1][tid] + redS[0][2][tid] + redS[0][3][tid];
                float q = redQ[0][0][tid] + redQ[0][1][tid] + redQ[0][2][tid] + redQ[0][3][tid];
                float m = s * (1.0f / B_);
                float v = q * (1.0f / B_) - m * m;
                cms[tid] = m;
                cis[tid] = rsqrtf(fmaxf(v, 0.f) + EPS_);
            }
            __syncthreads();
            {
                const float m = cms[lcol], is = cis[lcol];
                short* Hwh = Hh + (size_t)(l * 2 + pw) * B_ * H_;
                short* Hwl = Hl + (size_t)(l * 2 + pw) * B_ * H_;
#pragma unroll
                for (int mt = 0; mt < 2; ++mt)
#pragma unroll
                    for (int r = 0; r < 4; ++r) {
                        int row = wv * 32 + mt * 16 + quad * 4 + r;
                        float hv = sigm(osv[mt][r]) * tanhf((creg[mt][r] - m) * is * gcv + bcv);
                        short hi = f2bf(hv);
                        short lo = f2bf(hv - bf2f(hi));
                        Hwh[(size_t)row * H_ + jc] = hi;
                        Hwl[(size_t)row * H_ + jc] = lo;
                    }
            }
        }
        grid_barrier(&flags[d]);
    }
}

// ---------------------------------------------------------------------------
// Final linear + softmax: one WG per batch row.
// ---------------------------------------------------------------------------
__global__ void __launch_bounds__(256)
final_kernel(const short* __restrict__ Hh, const short* __restrict__ Hl,
             const float* __restrict__ Wlin, const float* __restrict__ blin,
             float* __restrict__ out) {
    const int b   = blockIdx.x;
    const int tid = threadIdx.x;
    __shared__ float hs[H_];
    __shared__ float rbuf[256];
    constexpr int lastPar = (ND - 1) & 1;  // = 0

    {
        size_t o = (size_t)((L_ - 1) * 2 + lastPar) * B_ * H_ + (size_t)b * H_ + tid;
        hs[tid] = bf2f(Hh[o]) + bf2f(Hl[o]);
    }
    __syncthreads();

    float lg[3];
#pragma unroll
    for (int r = 0; r < 3; ++r) {
        int cls = tid + r * 256;
        float a = -1e30f;
        if (cls < C_) {
            a = blin[cls];
            for (int j = 0; j < H_; ++j) a += hs[j] * Wlin[(size_t)j * C_ + cls];
        }
        lg[r] = a;
    }

    float mx = fmaxf(fmaxf(lg[0], lg[1]), lg[2]);
    rbuf[tid] = mx;
    __syncthreads();
    for (int s = 128; s > 0; s >>= 1) {
        if (tid < s) rbuf[tid] = fmaxf(rbuf[tid], rbuf[tid + s]);
        __syncthreads();
    }
    mx = rbuf[0];
    __syncthreads();

    float ev[3];
    float es = 0.f;
#pragma unroll
    for (int r = 0; r < 3; ++r) {
        int cls = tid + r * 256;
        if (cls < C_) { ev[r] = expf(lg[r] - mx); es += ev[r]; }
        else ev[r] = 0.f;
    }
    rbuf[tid] = es;
    __syncthreads();
    for (int s = 128; s > 0; s >>= 1) {
        if (tid < s) rbuf[tid] += rbuf[tid + s];
        __syncthreads();
    }
    const float inv = 1.f / rbuf[0];
#pragma unroll
    for (int r = 0; r < 3; ++r) {
        int cls = tid + r * 256;
        if (cls < C_) out[(size_t)b * C_ + cls] = ev[r] * inv;
    }
}

// ---------------------------------------------------------------------------
extern "C" void kernel_launch(void* const* d_in, const int* in_sizes, int n_in,
                              void* d_out, int out_size, void* d_ws, size_t ws_size,
                              hipStream_t stream) {
    const float* seq  = (const float*)d_in[0];
    const float* Wih0 = (const float*)d_in[1];
    const float* Wih  = (const float*)d_in[2];
    const float* Whh  = (const float*)d_in[3];
    const float* bias = (const float*)d_in[4];
    const float* gih  = (const float*)d_in[5];
    const float* bih  = (const float*)d_in[6];
    const float* ghh  = (const float*)d_in[7];
    const float* bhh  = (const float*)d_in[8];
    const float* gc   = (const float*)d_in[9];
    const float* bc   = (const float*)d_in[10];
    const float* Wlin = (const float*)d_in[11];
    const float* blin = (const float*)d_in[12];
    float* out = (float*)d_out;

    // workspace: flags(4KB) + Hh(2MB) + Hl(2MB) + Wth(16.25MB) + Wtl(16.25MB)
    unsigned* flags = (unsigned*)d_ws;                   // 1024 slots (ND=167 used)
    short* Hh  = (short*)d_ws + 2048;                    // byte offset 4096
    short* Hl  = Hh + (size_t)L_ * 2 * B_ * H_;
    short* Wth = Hl + (size_t)L_ * 2 * B_ * H_;
    short* Wtl = Wth + (size_t)NMAT * MATSZ;

    // zero barrier flags + both H planes (ws is poisoned 0xAA before each call)
    hipMemsetAsync(d_ws, 0, 4096 + (size_t)L_ * 2 * B_ * H_ * 2 * sizeof(short), stream);

    prep_kernel<<<dim3(16, 4, NMAT), 256, 0, stream>>>(Wih, Whh, Wth, Wtl);

    wave_kernel<<<dim3(NBLK), dim3(256), 0, stream>>>(Wth, Wtl, Wih0, seq, bias,
                                                      gih, bih, ghh, bhh, gc, bc,
                                                      Hh, Hl, flags);

    final_kernel<<<B_, 256, 0, stream>>>(Hh, Hl, Wlin, blin, out);
}

// Round 5
// 6511.230 us; speedup vs baseline: 2.2359x; 1.1084x over previous
//
#include <hip/hip_runtime.h>

typedef short s16x8 __attribute__((ext_vector_type(8)));
typedef float f32x4 __attribute__((ext_vector_type(4)));

constexpr int B_  = 128;
constexpr int T_  = 152;
constexpr int I_  = 75;
constexpr int H_  = 256;
constexpr int L_  = 16;
constexpr int C_  = 625;
constexpr int G4  = 1024;          // 4*H
constexpr float EPS_ = 1e-5f;
constexpr int NBLK = 256;          // 16 layers x 16 col-groups
constexpr int ND  = T_ + L_ - 1;   // 167 diagonals
constexpr int NMAT = 31;           // 15 W_ih (layers 1..15) + 16 W_hh
constexpr size_t MATSZ = (size_t)G4 * H_;

constexpr int WSTRIDE = 264;               // padded LDS W row stride (shorts): 2-way-only conflicts
constexpr int WPL_SH  = 64 * WSTRIDE;      // shorts per W plane in LDS (16896)
constexpr int DYNLDS  = 4 * WPL_SH * 2;    // 135168 B dynamic arena
constexpr int FLAGSTR = 32;                // u32 per flag (128B line, no false sharing)

__device__ __forceinline__ f32x4 mfma16(s16x8 a, s16x8 b, f32x4 c) {
    return __builtin_amdgcn_mfma_f32_16x16x32_bf16(a, b, c, 0, 0, 0);
}
__device__ __forceinline__ float sigm(float x) { return 1.f / (1.f + expf(-x)); }
__device__ __forceinline__ short f2bf(float x) {
    __bf16 h = (__bf16)x; return __builtin_bit_cast(short, h);
}
__device__ __forceinline__ float bf2f(short s) {
    __bf16 h = __builtin_bit_cast(__bf16, s); return (float)h;
}

// ---------------------------------------------------------------------------
// Prep: transpose W (k,4H) -> (4H,k), split fp32 -> bf16 hi/lo planes.
// ---------------------------------------------------------------------------
__global__ void __launch_bounds__(256)
prep_kernel(const float* __restrict__ Wih, const float* __restrict__ Whh,
            short* __restrict__ Wth, short* __restrict__ Wtl) {
    __shared__ float tile[64][65];
    const int mat = blockIdx.z;
    const int n0  = blockIdx.x * 64;
    const int k0  = blockIdx.y * 64;
    const int tid = threadIdx.x;
    const float* src = (mat < 15) ? (Wih + (size_t)mat * MATSZ)
                                  : (Whh + (size_t)(mat - 15) * MATSZ);
#pragma unroll
    for (int r = 0; r < 16; ++r) {
        int idx = r * 256 + tid;
        int kk = idx >> 6, nn = idx & 63;
        tile[kk][nn] = src[(size_t)(k0 + kk) * G4 + n0 + nn];
    }
    __syncthreads();
#pragma unroll
    for (int r = 0; r < 16; ++r) {
        int idx = r * 256 + tid;
        int nn = idx >> 6, kk = idx & 63;
        float w = tile[kk][nn];
        short hi = f2bf(w);
        short lo = f2bf(w - bf2f(hi));
        size_t o = ((size_t)mat * G4 + n0 + nn) * H_ + k0 + kk;
        Wth[o] = hi;
        Wtl[o] = lo;
    }
}

// BN stats over batch (128 rows) per (gate, col). acc in MFMA C-layout.
__device__ __forceinline__ void bn_stats(
    const f32x4 acc[2][4], int tid,
    float (*redS)[4][16], float (*redQ)[4][16],
    float (*mvM)[16], float (*mvI)[16]) {
    const int lane = tid & 63;
    const int wv   = tid >> 6;
    const int lcol = lane & 15;
#pragma unroll
    for (int g = 0; g < 4; ++g) {
        float s = 0.f, q = 0.f;
#pragma unroll
        for (int mt = 0; mt < 2; ++mt)
#pragma unroll
            for (int r = 0; r < 4; ++r) { float a = acc[mt][g][r]; s += a; q += a * a; }
        s += __shfl_xor(s, 16); s += __shfl_xor(s, 32);
        q += __shfl_xor(q, 16); q += __shfl_xor(q, 32);
        if (lane < 16) { redS[g][wv][lcol] = s; redQ[g][wv][lcol] = q; }
    }
    __syncthreads();
    if (tid < 64) {
        int g = tid >> 4, c = tid & 15;
        float s = redS[g][0][c] + redS[g][1][c] + redS[g][2][c] + redS[g][3][c];
        float q = redQ[g][0][c] + redQ[g][1][c] + redQ[g][2][c] + redQ[g][3][c];
        float m = s * (1.0f / B_);
        float v = q * (1.0f / B_) - m * m;
        mvM[g][c] = m;
        mvI[g][c] = rsqrtf(fmaxf(v, 0.f) + EPS_);
    }
    __syncthreads();
}

// ---------------------------------------------------------------------------
// Wavefront kernel: 256 WGs, persistent W in dynamic LDS, direct-global A
// fragments, p2p layer flags (depth-4 H rotation).
// Arena: Wr_hi @0, Wr_lo @+16896, Wi_hi @+33792, Wi_lo @+50688 (short offs)
// l==0: Wi region reused as xs0 f32[128][77] @byte 67584, w0s @byte 107008
// ---------------------------------------------------------------------------
__global__ void __launch_bounds__(256, 1)
wave_kernel(const short* __restrict__ Wth, const short* __restrict__ Wtl,
            const float* __restrict__ Wih0, const float* __restrict__ seq,
            const float* __restrict__ bias,
            const float* __restrict__ g_ih, const float* __restrict__ b_ih,
            const float* __restrict__ g_hh, const float* __restrict__ b_hh,
            const float* __restrict__ g_c,  const float* __restrict__ b_c,
            short* __restrict__ Hh, short* __restrict__ Hl,
            unsigned* __restrict__ flags) {
    extern __shared__ char arena[];
    __shared__ float redS[4][4][16];
    __shared__ float redQ[4][4][16];
    __shared__ float mvM[4][16], mvI[4][16];
    __shared__ float cms[16], cis[16];

    short* Wr_hi = (short*)arena;
    short* Wr_lo = Wr_hi + WPL_SH;
    short* Wi_hi = Wr_lo + WPL_SH;
    short* Wi_lo = Wi_hi + WPL_SH;
    float* xs0   = (float*)(arena + 67584);    // l==0 only
    float* w0s   = (float*)(arena + 107008);   // l==0 only
    float* proj  = xs0;

    const int b    = blockIdx.x;
    const int l    = ((b & 7) << 1) | ((b >> 3) & 1);  // layers 2x,2x+1 per XCD
    const int gq   = b >> 4;
    const int j0   = gq * 16;
    const int tid  = threadIdx.x;
    const int lane = tid & 63;
    const int wv   = tid >> 6;
    const int quad = lane >> 4;
    const int lcol = lane & 15;
    const int jc   = j0 + lcol;
    const int tx   = tid & 15;
    const int ty4  = tid >> 4;

    float gihv[4], bihv[4], ghhv[4], bhhv[4], bsv[4];
#pragma unroll
    for (int g = 0; g < 4; ++g) {
        int col = l * G4 + g * H_ + jc;
        gihv[g] = g_ih[col];
        bihv[g] = b_ih[col];
        ghhv[g] = g_hh[col];
        bhhv[g] = b_hh[col];
        bsv[g]  = bias[col];
    }
    const float gcv = g_c[l * H_ + jc];
    const float bcv = b_c[l * H_ + jc];

    // ---- persistent weight preload (once) ----
    {
        const int row = tid >> 2, seg = (tid & 3) * 64;
        const int g = row >> 4, c = row & 15;
        const size_t srow = ((size_t)(g * H_ + j0 + c)) * H_ + seg;
        const short* sWrh = Wth + (size_t)(15 + l) * MATSZ + srow;
        const short* sWrl = Wtl + (size_t)(15 + l) * MATSZ + srow;
        short* dWrh = Wr_hi + row * WSTRIDE + seg;
        short* dWrl = Wr_lo + row * WSTRIDE + seg;
#pragma unroll
        for (int u = 0; u < 8; ++u) {
            *(s16x8*)(dWrh + u * 8) = *(const s16x8*)(sWrh + u * 8);
            *(s16x8*)(dWrl + u * 8) = *(const s16x8*)(sWrl + u * 8);
        }
        if (l > 0) {
            const short* sWih = Wth + (size_t)(l - 1) * MATSZ + srow;
            const short* sWil = Wtl + (size_t)(l - 1) * MATSZ + srow;
            short* dWih = Wi_hi + row * WSTRIDE + seg;
            short* dWil = Wi_lo + row * WSTRIDE + seg;
#pragma unroll
            for (int u = 0; u < 8; ++u) {
                *(s16x8*)(dWih + u * 8) = *(const s16x8*)(sWih + u * 8);
                *(s16x8*)(dWil + u * 8) = *(const s16x8*)(sWil + u * 8);
            }
        }
    }
    __syncthreads();

    f32x4 creg[2];
    creg[0] = (f32x4){0.f, 0.f, 0.f, 0.f};
    creg[1] = (f32x4){0.f, 0.f, 0.f, 0.f};

    const int arow0 = wv * 32 + lcol;          // A rows for mt=0 / +16 for mt=1
    const int koff  = quad * 8;

    for (int t = 0; t < T_; ++t) {
        const int d  = t + l;
        const int pr = (d - 1) & 3;
        const int pw = d & 3;

        // ---- p2p waits ----
        if (tid == 0) {
            if (l > 0) {
                volatile unsigned* f = &flags[(size_t)((l - 1) * ND + (d - 1)) * FLAGSTR];
                while (__hip_atomic_load((unsigned*)f, __ATOMIC_ACQUIRE,
                                         __HIP_MEMORY_SCOPE_AGENT) < 16u)
                    __builtin_amdgcn_s_sleep(1);
            }
            if (t >= 1) {
                volatile unsigned* f = &flags[(size_t)(l * ND + (d - 1)) * FLAGSTR];
                while (__hip_atomic_load((unsigned*)f, __ATOMIC_ACQUIRE,
                                         __HIP_MEMORY_SCOPE_AGENT) < 16u)
                    __builtin_amdgcn_s_sleep(1);
            }
            {
                int tb = d - 3 - (l + 1);
                if (l < 15 && tb >= 0 && tb < T_) {
                    volatile unsigned* f = &flags[(size_t)((l + 1) * ND + (d - 3)) * FLAGSTR];
                    while (__hip_atomic_load((unsigned*)f, __ATOMIC_ACQUIRE,
                                             __HIP_MEMORY_SCOPE_AGENT) < 16u)
                        __builtin_amdgcn_s_sleep(1);
                }
            }
        }
        __syncthreads();

        f32x4 accI[2][4], accR[2][4];
#pragma unroll
        for (int mt = 0; mt < 2; ++mt)
#pragma unroll
            for (int g = 0; g < 4; ++g) {
                accI[mt][g] = (f32x4){0.f, 0.f, 0.f, 0.f};
                accR[mt][g] = (f32x4){0.f, 0.f, 0.f, 0.f};
            }

        const short* XRh = Hh + (size_t)(l * 4 + pr) * B_ * H_;
        const short* XRl = Hl + (size_t)(l * 4 + pr) * B_ * H_;
        const short* XIh = (l > 0) ? (Hh + (size_t)((l - 1) * 4 + pr) * B_ * H_) : XRh;
        const short* XIl = (l > 0) ? (Hl + (size_t)((l - 1) * 4 + pr) * B_ * H_) : XRl;

        if (l == 0) {
            // ---- inline fp32 input projection x_t @ W0 (K=75) -> accI ----
            for (int idx = tid; idx < B_ * I_; idx += 256) {
                int row = idx / I_;
                int k   = idx - row * I_;
                xs0[row * 77 + k] = seq[(size_t)row * (T_ * I_) + t * I_ + k];
            }
            for (int idx = tid; idx < 64 * I_; idx += 256) {
                int k  = idx >> 6;
                int cc = idx & 63;
                w0s[k * 68 + cc] = Wih0[(size_t)k * G4 + (cc >> 4) * H_ + j0 + (cc & 15)];
            }
            __syncthreads();
            float pacc[8][4];
#pragma unroll
            for (int i = 0; i < 8; ++i)
#pragma unroll
                for (int c = 0; c < 4; ++c) pacc[i][c] = 0.f;
            for (int k = 0; k < I_; ++k) {
                float4 wvv = *(const float4*)&w0s[k * 68 + 4 * tx];
#pragma unroll
                for (int i = 0; i < 8; ++i) {
                    float xv = xs0[(ty4 + 16 * i) * 77 + k];
                    pacc[i][0] += xv * wvv.x;
                    pacc[i][1] += xv * wvv.y;
                    pacc[i][2] += xv * wvv.z;
                    pacc[i][3] += xv * wvv.w;
                }
            }
            __syncthreads();
#pragma unroll
            for (int i = 0; i < 8; ++i) {
                float4 o;
                o.x = pacc[i][0]; o.y = pacc[i][1]; o.z = pacc[i][2]; o.w = pacc[i][3];
                *(float4*)&proj[(ty4 + 16 * i) * 68 + 4 * tx] = o;
            }
            __syncthreads();
#pragma unroll
            for (int mt = 0; mt < 2; ++mt)
#pragma unroll
                for (int g = 0; g < 4; ++g)
#pragma unroll
                    for (int r = 0; r < 4; ++r)
                        accI[mt][g][r] = proj[(wv * 32 + mt * 16 + quad * 4 + r) * 68
                                              + g * 16 + lcol];
            __syncthreads();  // proj area free before next use
        }

        // ---- fused K-loop: rec GEMM (+ input GEMM if l>0), W from LDS,
        //      A direct from global, pipelined one k-step ahead ----
        {
            s16x8 arh0 = *(const s16x8*)&XRh[arow0 * H_ + koff];
            s16x8 arh1 = *(const s16x8*)&XRh[(arow0 + 16) * H_ + koff];
            s16x8 arl0 = *(const s16x8*)&XRl[arow0 * H_ + koff];
            s16x8 arl1 = *(const s16x8*)&XRl[(arow0 + 16) * H_ + koff];
            s16x8 aih0 = arh0, aih1 = arh1, ail0 = arl0, ail1 = arl1;
            if (l > 0) {
                aih0 = *(const s16x8*)&XIh[arow0 * H_ + koff];
                aih1 = *(const s16x8*)&XIh[(arow0 + 16) * H_ + koff];
                ail0 = *(const s16x8*)&XIl[arow0 * H_ + koff];
                ail1 = *(const s16x8*)&XIl[(arow0 + 16) * H_ + koff];
            }
#pragma unroll
            for (int ks = 0; ks < 8; ++ks) {
                s16x8 nrh0 = arh0, nrh1 = arh1, nrl0 = arl0, nrl1 = arl1;
                s16x8 nih0 = aih0, nih1 = aih1, nil0 = ail0, nil1 = ail1;
                if (ks < 7) {
                    const int ko = (ks + 1) * 32 + koff;
                    nrh0 = *(const s16x8*)&XRh[arow0 * H_ + ko];
                    nrh1 = *(const s16x8*)&XRh[(arow0 + 16) * H_ + ko];
                    nrl0 = *(const s16x8*)&XRl[arow0 * H_ + ko];
                    nrl1 = *(const s16x8*)&XRl[(arow0 + 16) * H_ + ko];
                    if (l > 0) {
                        nih0 = *(const s16x8*)&XIh[arow0 * H_ + ko];
                        nih1 = *(const s16x8*)&XIh[(arow0 + 16) * H_ + ko];
                        nil0 = *(const s16x8*)&XIl[arow0 * H_ + ko];
                        nil1 = *(const s16x8*)&XIl[(arow0 + 16) * H_ + ko];
                    }
                }
#pragma unroll
                for (int g = 0; g < 4; ++g) {
                    const int bo = (g * 16 + lcol) * WSTRIDE + ks * 32 + koff;
                    s16x8 brh = *(const s16x8*)&Wr_hi[bo];
                    s16x8 brl = *(const s16x8*)&Wr_lo[bo];
                    accR[0][g] = mfma16(arh0, brh, accR[0][g]);
                    accR[0][g] = mfma16(arl0, brh, accR[0][g]);
                    accR[0][g] = mfma16(arh0, brl, accR[0][g]);
                    accR[0][g] = mfma16(arl0, brl, accR[0][g]);
                    accR[1][g] = mfma16(arh1, brh, accR[1][g]);
                    accR[1][g] = mfma16(arl1, brh, accR[1][g]);
                    accR[1][g] = mfma16(arh1, brl, accR[1][g]);
                    accR[1][g] = mfma16(arl1, brl, accR[1][g]);
                    if (l > 0) {
                        s16x8 bih = *(const s16x8*)&Wi_hi[bo];
                        s16x8 bil = *(const s16x8*)&Wi_lo[bo];
                        accI[0][g] = mfma16(aih0, bih, accI[0][g]);
                        accI[0][g] = mfma16(ail0, bih, accI[0][g]);
                        accI[0][g] = mfma16(aih0, bil, accI[0][g]);
                        accI[0][g] = mfma16(ail0, bil, accI[0][g]);
                        accI[1][g] = mfma16(aih1, bih, accI[1][g]);
                        accI[1][g] = mfma16(ail1, bih, accI[1][g]);
                        accI[1][g] = mfma16(aih1, bil, accI[1][g]);
                        accI[1][g] = mfma16(ail1, bil, accI[1][g]);
                    }
                }
                arh0 = nrh0; arh1 = nrh1; arl0 = nrl0; arl1 = nrl1;
                aih0 = nih0; aih1 = nih1; ail0 = nil0; ail1 = nil1;
            }
        }

        // ---- BN(input proj) -> bnwi ----
        f32x4 bnwi[2][4];
        bn_stats(accI, tid, redS, redQ, mvM, mvI);
#pragma unroll
        for (int g = 0; g < 4; ++g) {
            float m = mvM[g][lcol], is = mvI[g][lcol];
#pragma unroll
            for (int mt = 0; mt < 2; ++mt)
#pragma unroll
                for (int r = 0; r < 4; ++r)
                    bnwi[mt][g][r] = (accI[mt][g][r] - m) * is * gihv[g] + bihv[g];
        }

        // ---- BN(recurrent) + gates ----
        bn_stats(accR, tid, redS, redQ, mvM, mvI);
        f32x4 osv[2];
#pragma unroll
        for (int mt = 0; mt < 2; ++mt) {
#pragma unroll
            for (int r = 0; r < 4; ++r) {
                float sf = (accR[mt][0][r] - mvM[0][lcol]) * mvI[0][lcol] * ghhv[0] + bhhv[0] + bnwi[mt][0][r] + bsv[0];
                float si = (accR[mt][1][r] - mvM[1][lcol]) * mvI[1][lcol] * ghhv[1] + bhhv[1] + bnwi[mt][1][r] + bsv[1];
                float so = (accR[mt][2][r] - mvM[2][lcol]) * mvI[2][lcol] * ghhv[2] + bhhv[2] + bnwi[mt][2][r] + bsv[2];
                float sg = (accR[mt][3][r] - mvM[3][lcol]) * mvI[3][lcol] * ghhv[3] + bhhv[3] + bnwi[mt][3][r] + bsv[3];
                creg[mt][r] = sigm(sf) * creg[mt][r] + sigm(si) * tanhf(sg);
                osv[mt][r]  = so;
            }
        }

        // ---- BN over c ----
        {
            float s = 0.f, q = 0.f;
#pragma unroll
            for (int mt = 0; mt < 2; ++mt)
#pragma unroll
                for (int r = 0; r < 4; ++r) { float a = creg[mt][r]; s += a; q += a * a; }
            s += __shfl_xor(s, 16); s += __shfl_xor(s, 32);
            q += __shfl_xor(q, 16); q += __shfl_xor(q, 32);
            if (lane < 16) { redS[0][wv][lcol] = s; redQ[0][wv][lcol] = q; }
        }
        __syncthreads();
        if (tid < 16) {
            float s = redS[0][0][tid] + redS[0][1][tid] + redS[0][2][tid] + redS[0][3][tid];
            float q = redQ[0][0][tid] + redQ[0][1][tid] + redQ[0][2][tid] + redQ[0][3][tid];
            float m = s * (1.0f / B_);
            float v = q * (1.0f / B_) - m * m;
            cms[tid] = m;
            cis[tid] = rsqrtf(fmaxf(v, 0.f) + EPS_);
        }
        __syncthreads();
        {
            const float m = cms[lcol], is = cis[lcol];
            short* Hwh = Hh + (size_t)(l * 4 + pw) * B_ * H_;
            short* Hwl = Hl + (size_t)(l * 4 + pw) * B_ * H_;
#pragma unroll
            for (int mt = 0; mt < 2; ++mt)
#pragma unroll
                for (int r = 0; r < 4; ++r) {
                    int row = wv * 32 + mt * 16 + quad * 4 + r;
                    float hv = sigm(osv[mt][r]) * tanhf((creg[mt][r] - m) * is * gcv + bcv);
                    short hi = f2bf(hv);
                    short lo = f2bf(hv - bf2f(hi));
                    Hwh[(size_t)row * H_ + jc] = hi;
                    Hwl[(size_t)row * H_ + jc] = lo;
                }
        }
        __syncthreads();
        if (tid == 0) {
            __threadfence();
            __hip_atomic_fetch_add(&flags[(size_t)(l * ND + d) * FLAGSTR], 1u,
                                   __ATOMIC_ACQ_REL, __HIP_MEMORY_SCOPE_AGENT);
        }
    }
}

// ---------------------------------------------------------------------------
// Final linear + softmax: one WG per batch row.
// ---------------------------------------------------------------------------
__global__ void __launch_bounds__(256)
final_kernel(const short* __restrict__ Hh, const short* __restrict__ Hl,
             const float* __restrict__ Wlin, const float* __restrict__ blin,
             float* __restrict__ out) {
    const int b   = blockIdx.x;
    const int tid = threadIdx.x;
    __shared__ float hs[H_];
    __shared__ float rbuf[256];
    constexpr int lastPar = (ND - 1) & 3;  // = 2

    {
        size_t o = (size_t)((L_ - 1) * 4 + lastPar) * B_ * H_ + (size_t)b * H_ + tid;
        hs[tid] = bf2f(Hh[o]) + bf2f(Hl[o]);
    }
    __syncthreads();

    float lg[3];
#pragma unroll
    for (int r = 0; r < 3; ++r) {
        int cls = tid + r * 256;
        float a = -1e30f;
        if (cls < C_) {
            a = blin[cls];
            for (int j = 0; j < H_; ++j) a += hs[j] * Wlin[(size_t)j * C_ + cls];
        }
        lg[r] = a;
    }

    float mx = fmaxf(fmaxf(lg[0], lg[1]), lg[2]);
    rbuf[tid] = mx;
    __syncthreads();
    for (int s = 128; s > 0; s >>= 1) {
        if (tid < s) rbuf[tid] = fmaxf(rbuf[tid], rbuf[tid + s]);
        __syncthreads();
    }
    mx = rbuf[0];
    __syncthreads();

    float ev[3];
    float es = 0.f;
#pragma unroll
    for (int r = 0; r < 3; ++r) {
        int cls = tid + r * 256;
        if (cls < C_) { ev[r] = expf(lg[r] - mx); es += ev[r]; }
        else ev[r] = 0.f;
    }
    rbuf[tid] = es;
    __syncthreads();
    for (int s = 128; s > 0; s >>= 1) {
        if (tid < s) rbuf[tid] += rbuf[tid + s];
        __syncthreads();
    }
    const float inv = 1.f / rbuf[0];
#pragma unroll
    for (int r = 0; r < 3; ++r) {
        int cls = tid + r * 256;
        if (cls < C_) out[(size_t)b * C_ + cls] = ev[r] * inv;
    }
}

// ---------------------------------------------------------------------------
extern "C" void kernel_launch(void* const* d_in, const int* in_sizes, int n_in,
                              void* d_out, int out_size, void* d_ws, size_t ws_size,
                              hipStream_t stream) {
    const float* seq  = (const float*)d_in[0];
    const float* Wih0 = (const float*)d_in[1];
    const float* Wih  = (const float*)d_in[2];
    const float* Whh  = (const float*)d_in[3];
    const float* bias = (const float*)d_in[4];
    const float* gih  = (const float*)d_in[5];
    const float* bih  = (const float*)d_in[6];
    const float* ghh  = (const float*)d_in[7];
    const float* bhh  = (const float*)d_in[8];
    const float* gc   = (const float*)d_in[9];
    const float* bc   = (const float*)d_in[10];
    const float* Wlin = (const float*)d_in[11];
    const float* blin = (const float*)d_in[12];
    float* out = (float*)d_out;

    // ws: flags @0 (342KB used, 512KB reserved) | Hh 4MB | Hl 4MB | Wth | Wtl
    constexpr size_t FLAGRES = 1u << 19;
    constexpr size_t HSZ = (size_t)L_ * 4 * B_ * H_;   // shorts per H plane set
    unsigned* flags = (unsigned*)d_ws;
    short* Hh  = (short*)((char*)d_ws + FLAGRES);
    short* Hl  = Hh + HSZ;
    short* Wth = Hl + HSZ;
    short* Wtl = Wth + (size_t)NMAT * MATSZ;

    hipMemsetAsync(d_ws, 0, FLAGRES + 2 * HSZ * sizeof(short), stream);

    prep_kernel<<<dim3(16, 4, NMAT), 256, 0, stream>>>(Wih, Whh, Wth, Wtl);

    hipFuncSetAttribute((const void*)wave_kernel,
                        hipFuncAttributeMaxDynamicSharedMemorySize, DYNLDS);
    wave_kernel<<<dim3(NBLK), dim3(256), DYNLDS, stream>>>(
        Wth, Wtl, Wih0, seq, bias, gih, bih, ghh, bhh, gc, bc, Hh, Hl, flags);

    final_kernel<<<B_, 256, 0, stream>>>(Hh, Hl, Wlin, blin, out);
}

// Round 6
// 4959.082 us; speedup vs baseline: 2.9357x; 1.3130x over previous
//
#include <hip/hip_runtime.h>

typedef short s16x8 __attribute__((ext_vector_type(8)));
typedef float f32x4 __attribute__((ext_vector_type(4)));

constexpr int B_  = 128;
constexpr int T_  = 152;
constexpr int I_  = 75;
constexpr int H_  = 256;
constexpr int L_  = 16;
constexpr int C_  = 625;
constexpr int G4  = 1024;          // 4*H
constexpr float EPS_ = 1e-5f;
constexpr int NBLK = 256;          // 16 layers x 16 col-groups
constexpr int ND  = T_ + L_ - 1;   // 167 diagonals
constexpr int NMAT2 = 32;          // 15 W_ih + 16 W_hh + 1 W0^T(padded)
constexpr size_t MATSZ = (size_t)G4 * H_;

constexpr int WSTRIDE = 266;               // 133 dwords, odd mod 32 -> <=2-way LDS conflicts
constexpr int WPL_SH  = 64 * WSTRIDE;      // shorts per W plane in LDS (17024)
constexpr int DYNLDS  = 4 * WPL_SH * 2;    // 136192 B dynamic arena
constexpr int FLAGSTR = 32;                // u32 per flag slot (128B line)
constexpr int XK      = 96;                // padded K for layer-0 input (75 -> 96)

__device__ __forceinline__ f32x4 mfma16(s16x8 a, s16x8 b, f32x4 c) {
    return __builtin_amdgcn_mfma_f32_16x16x32_bf16(a, b, c, 0, 0, 0);
}
__device__ __forceinline__ float sigm(float x) { return 1.f / (1.f + expf(-x)); }
__device__ __forceinline__ short f2bf(float x) {
    __bf16 h = (__bf16)x; return __builtin_bit_cast(short, h);
}
__device__ __forceinline__ float bf2f(short s) {
    __bf16 h = __builtin_bit_cast(__bf16, s); return (float)h;
}

// ---------------------------------------------------------------------------
// Prep: transpose W (k,4H) -> (4H,k), split fp32 -> bf16 hi/lo planes. 31 mats.
// ---------------------------------------------------------------------------
__global__ void __launch_bounds__(256)
prep_kernel(const float* __restrict__ Wih, const float* __restrict__ Whh,
            short* __restrict__ Wth, short* __restrict__ Wtl) {
    __shared__ float tile[64][65];
    const int mat = blockIdx.z;
    const int n0  = blockIdx.x * 64;
    const int k0  = blockIdx.y * 64;
    const int tid = threadIdx.x;
    const float* src = (mat < 15) ? (Wih + (size_t)mat * MATSZ)
                                  : (Whh + (size_t)(mat - 15) * MATSZ);
#pragma unroll
    for (int r = 0; r < 16; ++r) {
        int idx = r * 256 + tid;
        int kk = idx >> 6, nn = idx & 63;
        tile[kk][nn] = src[(size_t)(k0 + kk) * G4 + n0 + nn];
    }
    __syncthreads();
#pragma unroll
    for (int r = 0; r < 16; ++r) {
        int idx = r * 256 + tid;
        int nn = idx >> 6, kk = idx & 63;
        float w = tile[kk][nn];
        short hi = f2bf(w);
        short lo = f2bf(w - bf2f(hi));
        size_t o = ((size_t)mat * G4 + n0 + nn) * H_ + k0 + kk;
        Wth[o] = hi;
        Wtl[o] = lo;
    }
}

// W0^T (75,1024) -> slot 31 (1024 rows, K padded to 256 with zeros; 0..95 used)
__global__ void __launch_bounds__(256)
prep_w0(const float* __restrict__ Wih0, short* __restrict__ Wth, short* __restrict__ Wtl) {
    const int n = blockIdx.x;
    const int k = threadIdx.x;
    float w = (k < I_) ? Wih0[(size_t)k * G4 + n] : 0.f;
    short hi = f2bf(w);
    short lo = f2bf(w - bf2f(hi));
    size_t o = ((size_t)31 * G4 + n) * H_ + k;
    Wth[o] = hi;
    Wtl[o] = lo;
}

// seq (B,T,I) -> Xp[t][row][0..95] bf16 hi/lo planes (zero-padded K)
__global__ void __launch_bounds__(256)
prep_x(const float* __restrict__ seq, short* __restrict__ Xph, short* __restrict__ Xpl) {
    const int t = blockIdx.x;
    for (int idx = threadIdx.x; idx < B_ * XK; idx += 256) {
        int row = idx / XK, k = idx - row * XK;
        float v = (k < I_) ? seq[(size_t)row * T_ * I_ + (size_t)t * I_ + k] : 0.f;
        short hi = f2bf(v);
        short lo = f2bf(v - bf2f(hi));
        size_t o = ((size_t)t * B_ + row) * XK + k;
        Xph[o] = hi;
        Xpl[o] = lo;
    }
}

// BN stats for 8 groups (4 input gates, 4 recurrent gates) in one pass.
__device__ __forceinline__ void bn_stats8(
    const f32x4 aI[2][4], const f32x4 aR[2][4], int tid,
    float (*redS)[4][16], float (*redQ)[4][16],   // [8][4][16]
    float (*mvM)[16], float (*mvI)[16]) {         // [8][16]
    const int lane = tid & 63;
    const int wv   = tid >> 6;
    const int lcol = lane & 15;
#pragma unroll
    for (int g = 0; g < 8; ++g) {
        float s = 0.f, q = 0.f;
#pragma unroll
        for (int mt = 0; mt < 2; ++mt) {
            const f32x4& v = (g < 4) ? aI[mt][g] : aR[mt][g - 4];
#pragma unroll
            for (int r = 0; r < 4; ++r) { float a = v[r]; s += a; q += a * a; }
        }
        s += __shfl_xor(s, 16); s += __shfl_xor(s, 32);
        q += __shfl_xor(q, 16); q += __shfl_xor(q, 32);
        if (lane < 16) { redS[g][wv][lcol] = s; redQ[g][wv][lcol] = q; }
    }
    __syncthreads();
    if (tid < 128) {
        int g = tid >> 4, c = tid & 15;
        float s = redS[g][0][c] + redS[g][1][c] + redS[g][2][c] + redS[g][3][c];
        float q = redQ[g][0][c] + redQ[g][1][c] + redQ[g][2][c] + redQ[g][3][c];
        float m = s * (1.0f / B_);
        float v = q * (1.0f / B_) - m * m;
        mvM[g][c] = m;
        mvI[g][c] = rsqrtf(fmaxf(v, 0.f) + EPS_);
    }
    __syncthreads();
}

// ---------------------------------------------------------------------------
// Wavefront kernel: 256 WGs, persistent W in LDS, p2p flags with relaxed
// polling + once-per-step acquire; sc1 (agent) H stores; uniform MFMA path
// for all layers (layer 0 uses Xp + W0^T, ksI=3).
// ---------------------------------------------------------------------------
__global__ void __launch_bounds__(256, 1)
wave_kernel(const short* __restrict__ Wth, const short* __restrict__ Wtl,
            const short* __restrict__ Xph, const short* __restrict__ Xpl,
            const float* __restrict__ bias,
            const float* __restrict__ g_ih, const float* __restrict__ b_ih,
            const float* __restrict__ g_hh, const float* __restrict__ b_hh,
            const float* __restrict__ g_c,  const float* __restrict__ b_c,
            short* __restrict__ Hh, short* __restrict__ Hl,
            unsigned* __restrict__ flags) {
    extern __shared__ char arena[];
    __shared__ float redS[8][4][16];
    __shared__ float redQ[8][4][16];
    __shared__ float mvM[8][16], mvI[8][16];
    __shared__ float cms[16], cis[16];

    short* Wr_hi = (short*)arena;
    short* Wr_lo = Wr_hi + WPL_SH;
    short* Wi_hi = Wr_lo + WPL_SH;
    short* Wi_lo = Wi_hi + WPL_SH;

    const int b    = blockIdx.x;
    const int l    = ((b & 7) << 1) | ((b >> 3) & 1);  // layers 2x,2x+1 per XCD
    const int gq   = b >> 4;
    const int j0   = gq * 16;
    const int tid  = threadIdx.x;
    const int lane = tid & 63;
    const int wv   = tid >> 6;
    const int quad = lane >> 4;
    const int lcol = lane & 15;
    const int jc   = j0 + lcol;

    float gihv[4], bihv[4], ghhv[4], bhhv[4], bsv[4];
#pragma unroll
    for (int g = 0; g < 4; ++g) {
        int col = l * G4 + g * H_ + jc;
        gihv[g] = g_ih[col];
        bihv[g] = b_ih[col];
        ghhv[g] = g_hh[col];
        bhhv[g] = b_hh[col];
        bsv[g]  = bias[col];
    }
    const float gcv = g_c[l * H_ + jc];
    const float bcv = b_c[l * H_ + jc];

    // ---- persistent weight preload (once): Wr = Whh[l] (slot 15+l),
    //      Wi = Wih[l-1] (slot l-1) or W0^T (slot 31) ----
    {
        const int row = tid >> 2, seg = (tid & 3) * 64;
        const int g = row >> 4, c = row & 15;
        const size_t srow = ((size_t)(g * H_ + j0 + c)) * H_ + seg;
        const int miI = (l > 0) ? (l - 1) : 31;
        const short* sWrh = Wth + (size_t)(15 + l) * MATSZ + srow;
        const short* sWrl = Wtl + (size_t)(15 + l) * MATSZ + srow;
        const short* sWih = Wth + (size_t)miI * MATSZ + srow;
        const short* sWil = Wtl + (size_t)miI * MATSZ + srow;
        short* dWrh = Wr_hi + row * WSTRIDE + seg;
        short* dWrl = Wr_lo + row * WSTRIDE + seg;
        short* dWih = Wi_hi + row * WSTRIDE + seg;
        short* dWil = Wi_lo + row * WSTRIDE + seg;
#pragma unroll
        for (int u = 0; u < 8; ++u) {
            *(s16x8*)(dWrh + u * 8) = *(const s16x8*)(sWrh + u * 8);
            *(s16x8*)(dWrl + u * 8) = *(const s16x8*)(sWrl + u * 8);
            *(s16x8*)(dWih + u * 8) = *(const s16x8*)(sWih + u * 8);
            *(s16x8*)(dWil + u * 8) = *(const s16x8*)(sWil + u * 8);
        }
    }
    __syncthreads();

    f32x4 creg[2];
    creg[0] = (f32x4){0.f, 0.f, 0.f, 0.f};
    creg[1] = (f32x4){0.f, 0.f, 0.f, 0.f};

    const int arow0 = wv * 32 + lcol;
    const int koff  = quad * 8;

    for (int t = 0; t < T_; ++t) {
        const int d  = t + l;
        const int pr = (d - 1) & 3;
        const int pw = d & 3;

        // ---- wait: relaxed polling, acquire once ----
        unsigned* fB = (l > 0)  ? &flags[(size_t)((l - 1) * ND + (d - 1)) * FLAGSTR] : nullptr;
        unsigned* fO = (t >= 1) ? &flags[(size_t)(l * ND + (d - 1)) * FLAGSTR] : nullptr;
        unsigned* fW = (l < 15 && t >= 4)
                       ? &flags[(size_t)((l + 1) * ND + (d - 3)) * FLAGSTR] : nullptr;
        if (tid == 0) {
            for (;;) {
                bool ok = true;
                if (fB && __hip_atomic_load(fB, __ATOMIC_RELAXED,
                                            __HIP_MEMORY_SCOPE_AGENT) < 16u) ok = false;
                if (ok && fO && __hip_atomic_load(fO, __ATOMIC_RELAXED,
                                                  __HIP_MEMORY_SCOPE_AGENT) < 16u) ok = false;
                if (ok && fW && __hip_atomic_load(fW, __ATOMIC_RELAXED,
                                                  __HIP_MEMORY_SCOPE_AGENT) < 16u) ok = false;
                if (ok) break;
                __builtin_amdgcn_s_sleep(1);
            }
        }
        __syncthreads();
        {
            unsigned* fa = fO ? fO : fB;
            if (fa) (void)__hip_atomic_load(fa, __ATOMIC_ACQUIRE, __HIP_MEMORY_SCOPE_AGENT);
        }

        // ---- fused K-loop ----
        f32x4 accI[2][4], accR[2][4];
#pragma unroll
        for (int mt = 0; mt < 2; ++mt)
#pragma unroll
            for (int g = 0; g < 4; ++g) {
                accI[mt][g] = (f32x4){0.f, 0.f, 0.f, 0.f};
                accR[mt][g] = (f32x4){0.f, 0.f, 0.f, 0.f};
            }

        const short* XRh = Hh + (size_t)(l * 4 + pr) * B_ * H_;
        const short* XRl = Hl + (size_t)(l * 4 + pr) * B_ * H_;
        const short* XIh; const short* XIl; int xis, ksI;
        if (l > 0) {
            XIh = Hh + (size_t)((l - 1) * 4 + pr) * B_ * H_;
            XIl = Hl + (size_t)((l - 1) * 4 + pr) * B_ * H_;
            xis = H_; ksI = 8;
        } else {
            XIh = Xph + (size_t)t * B_ * XK;
            XIl = Xpl + (size_t)t * B_ * XK;
            xis = XK; ksI = 3;
        }

#pragma unroll
        for (int ks = 0; ks < 8; ++ks) {
            const int ko = ks * 32 + koff;
            s16x8 arh0 = *(const s16x8*)&XRh[(size_t)arow0 * H_ + ko];
            s16x8 arh1 = *(const s16x8*)&XRh[(size_t)(arow0 + 16) * H_ + ko];
            s16x8 arl0 = *(const s16x8*)&XRl[(size_t)arow0 * H_ + ko];
            s16x8 arl1 = *(const s16x8*)&XRl[(size_t)(arow0 + 16) * H_ + ko];
            const bool doI = (ks < ksI);
            s16x8 aih0{}, aih1{}, ail0{}, ail1{};
            if (doI) {
                aih0 = *(const s16x8*)&XIh[(size_t)arow0 * xis + ko];
                aih1 = *(const s16x8*)&XIh[(size_t)(arow0 + 16) * xis + ko];
                ail0 = *(const s16x8*)&XIl[(size_t)arow0 * xis + ko];
                ail1 = *(const s16x8*)&XIl[(size_t)(arow0 + 16) * xis + ko];
            }
#pragma unroll
            for (int g = 0; g < 4; ++g) {
                const int bo = (g * 16 + lcol) * WSTRIDE + ko;
                s16x8 brh = *(const s16x8*)&Wr_hi[bo];
                s16x8 brl = *(const s16x8*)&Wr_lo[bo];
                accR[0][g] = mfma16(arh0, brh, accR[0][g]);
                accR[0][g] = mfma16(arl0, brh, accR[0][g]);
                accR[0][g] = mfma16(arh0, brl, accR[0][g]);
                accR[0][g] = mfma16(arl0, brl, accR[0][g]);
                accR[1][g] = mfma16(arh1, brh, accR[1][g]);
                accR[1][g] = mfma16(arl1, brh, accR[1][g]);
                accR[1][g] = mfma16(arh1, brl, accR[1][g]);
                accR[1][g] = mfma16(arl1, brl, accR[1][g]);
                if (doI) {
                    s16x8 bih = *(const s16x8*)&Wi_hi[bo];
                    s16x8 bil = *(const s16x8*)&Wi_lo[bo];
                    accI[0][g] = mfma16(aih0, bih, accI[0][g]);
                    accI[0][g] = mfma16(ail0, bih, accI[0][g]);
                    accI[0][g] = mfma16(aih0, bil, accI[0][g]);
                    accI[0][g] = mfma16(ail0, bil, accI[0][g]);
                    accI[1][g] = mfma16(aih1, bih, accI[1][g]);
                    accI[1][g] = mfma16(ail1, bih, accI[1][g]);
                    accI[1][g] = mfma16(aih1, bil, accI[1][g]);
                    accI[1][g] = mfma16(ail1, bil, accI[1][g]);
                }
            }
        }

        // ---- BN stats for both GEMMs (one pass) ----
        bn_stats8(accI, accR, tid, redS, redQ, mvM, mvI);

        f32x4 bnwi[2][4];
#pragma unroll
        for (int g = 0; g < 4; ++g) {
            float m = mvM[g][lcol], is = mvI[g][lcol];
#pragma unroll
            for (int mt = 0; mt < 2; ++mt)
#pragma unroll
                for (int r = 0; r < 4; ++r)
                    bnwi[mt][g][r] = (accI[mt][g][r] - m) * is * gihv[g] + bihv[g];
        }

        f32x4 osv[2];
#pragma unroll
        for (int mt = 0; mt < 2; ++mt) {
#pragma unroll
            for (int r = 0; r < 4; ++r) {
                float sf = (accR[mt][0][r] - mvM[4][lcol]) * mvI[4][lcol] * ghhv[0] + bhhv[0] + bnwi[mt][0][r] + bsv[0];
                float si = (accR[mt][1][r] - mvM[5][lcol]) * mvI[5][lcol] * ghhv[1] + bhhv[1] + bnwi[mt][1][r] + bsv[1];
                float so = (accR[mt][2][r] - mvM[6][lcol]) * mvI[6][lcol] * ghhv[2] + bhhv[2] + bnwi[mt][2][r] + bsv[2];
                float sg = (accR[mt][3][r] - mvM[7][lcol]) * mvI[7][lcol] * ghhv[3] + bhhv[3] + bnwi[mt][3][r] + bsv[3];
                creg[mt][r] = sigm(sf) * creg[mt][r] + sigm(si) * tanhf(sg);
                osv[mt][r]  = so;
            }
        }

        // ---- BN over c ----
        {
            float s = 0.f, q = 0.f;
#pragma unroll
            for (int mt = 0; mt < 2; ++mt)
#pragma unroll
                for (int r = 0; r < 4; ++r) { float a = creg[mt][r]; s += a; q += a * a; }
            s += __shfl_xor(s, 16); s += __shfl_xor(s, 32);
            q += __shfl_xor(q, 16); q += __shfl_xor(q, 32);
            if (lane < 16) { redS[0][wv][lcol] = s; redQ[0][wv][lcol] = q; }
        }
        __syncthreads();
        if (tid < 16) {
            float s = redS[0][0][tid] + redS[0][1][tid] + redS[0][2][tid] + redS[0][3][tid];
            float q = redQ[0][0][tid] + redQ[0][1][tid] + redQ[0][2][tid] + redQ[0][3][tid];
            float m = s * (1.0f / B_);
            float v = q * (1.0f / B_) - m * m;
            cms[tid] = m;
            cis[tid] = rsqrtf(fmaxf(v, 0.f) + EPS_);
        }
        __syncthreads();
        {
            const float m = cms[lcol], is = cis[lcol];
            short* Hwh = Hh + (size_t)(l * 4 + pw) * B_ * H_;
            short* Hwl = Hl + (size_t)(l * 4 + pw) * B_ * H_;
#pragma unroll
            for (int mt = 0; mt < 2; ++mt)
#pragma unroll
                for (int r = 0; r < 4; ++r) {
                    int row = wv * 32 + mt * 16 + quad * 4 + r;
                    float hv = sigm(osv[mt][r]) * tanhf((creg[mt][r] - m) * is * gcv + bcv);
                    short hi = f2bf(hv);
                    short lo = f2bf(hv - bf2f(hi));
                    __hip_atomic_store(&Hwh[(size_t)row * H_ + jc], hi,
                                       __ATOMIC_RELAXED, __HIP_MEMORY_SCOPE_AGENT);
                    __hip_atomic_store(&Hwl[(size_t)row * H_ + jc], lo,
                                       __ATOMIC_RELAXED, __HIP_MEMORY_SCOPE_AGENT);
                }
        }
        __syncthreads();   // drains vmcnt: all threads' sc1 stores complete
        if (tid == 0)
            __hip_atomic_fetch_add(&flags[(size_t)(l * ND + d) * FLAGSTR], 1u,
                                   __ATOMIC_RELEASE, __HIP_MEMORY_SCOPE_AGENT);
    }
}

// ---------------------------------------------------------------------------
// Final linear + softmax: one WG per batch row.
// ---------------------------------------------------------------------------
__global__ void __launch_bounds__(256)
final_kernel(const short* __restrict__ Hh, const short* __restrict__ Hl,
             const float* __restrict__ Wlin, const float* __restrict__ blin,
             float* __restrict__ out) {
    const int b   = blockIdx.x;
    const int tid = threadIdx.x;
    __shared__ float hs[H_];
    __shared__ float rbuf[256];
    constexpr int lastPar = (ND - 1) & 3;  // = 2

    {
        size_t o = (size_t)((L_ - 1) * 4 + lastPar) * B_ * H_ + (size_t)b * H_ + tid;
        hs[tid] = bf2f(Hh[o]) + bf2f(Hl[o]);
    }
    __syncthreads();

    float lg[3];
#pragma unroll
    for (int r = 0; r < 3; ++r) {
        int cls = tid + r * 256;
        float a = -1e30f;
        if (cls < C_) {
            a = blin[cls];
            for (int j = 0; j < H_; ++j) a += hs[j] * Wlin[(size_t)j * C_ + cls];
        }
        lg[r] = a;
    }

    float mx = fmaxf(fmaxf(lg[0], lg[1]), lg[2]);
    rbuf[tid] = mx;
    __syncthreads();
    for (int s = 128; s > 0; s >>= 1) {
        if (tid < s) rbuf[tid] = fmaxf(rbuf[tid], rbuf[tid + s]);
        __syncthreads();
    }
    mx = rbuf[0];
    __syncthreads();

    float ev[3];
    float es = 0.f;
#pragma unroll
    for (int r = 0; r < 3; ++r) {
        int cls = tid + r * 256;
        if (cls < C_) { ev[r] = expf(lg[r] - mx); es += ev[r]; }
        else ev[r] = 0.f;
    }
    rbuf[tid] = es;
    __syncthreads();
    for (int s = 128; s > 0; s >>= 1) {
        if (tid < s) rbuf[tid] += rbuf[tid + s];
        __syncthreads();
    }
    const float inv = 1.f / rbuf[0];
#pragma unroll
    for (int r = 0; r < 3; ++r) {
        int cls = tid + r * 256;
        if (cls < C_) out[(size_t)b * C_ + cls] = ev[r] * inv;
    }
}

// ---------------------------------------------------------------------------
extern "C" void kernel_launch(void* const* d_in, const int* in_sizes, int n_in,
                              void* d_out, int out_size, void* d_ws, size_t ws_size,
                              hipStream_t stream) {
    const float* seq  = (const float*)d_in[0];
    const float* Wih0 = (const float*)d_in[1];
    const float* Wih  = (const float*)d_in[2];
    const float* Whh  = (const float*)d_in[3];
    const float* bias = (const float*)d_in[4];
    const float* gih  = (const float*)d_in[5];
    const float* bih  = (const float*)d_in[6];
    const float* ghh  = (const float*)d_in[7];
    const float* bhh  = (const float*)d_in[8];
    const float* gc   = (const float*)d_in[9];
    const float* bc   = (const float*)d_in[10];
    const float* Wlin = (const float*)d_in[11];
    const float* blin = (const float*)d_in[12];
    float* out = (float*)d_out;

    // ws: flags 512KB | Hh 4MB | Hl 4MB | Wth 16.8MB | Wtl 16.8MB | Xph | Xpl (~50MB)
    constexpr size_t FLAGRES = 1u << 19;
    constexpr size_t HSZ = (size_t)L_ * 4 * B_ * H_;   // shorts per H plane set
    constexpr size_t XSZ = (size_t)T_ * B_ * XK;       // shorts per Xp plane
    unsigned* flags = (unsigned*)d_ws;
    short* Hh  = (short*)((char*)d_ws + FLAGRES);
    short* Hl  = Hh + HSZ;
    short* Wth = Hl + HSZ;
    short* Wtl = Wth + (size_t)NMAT2 * MATSZ;
    short* Xph = Wtl + (size_t)NMAT2 * MATSZ;
    short* Xpl = Xph + XSZ;

    hipMemsetAsync(d_ws, 0, FLAGRES + 2 * HSZ * sizeof(short), stream);

    prep_kernel<<<dim3(16, 4, 31), 256, 0, stream>>>(Wih, Whh, Wth, Wtl);
    prep_w0<<<dim3(G4), 256, 0, stream>>>(Wih0, Wth, Wtl);
    prep_x<<<dim3(T_), 256, 0, stream>>>(seq, Xph, Xpl);

    hipFuncSetAttribute((const void*)wave_kernel,
                        hipFuncAttributeMaxDynamicSharedMemorySize, DYNLDS);
    wave_kernel<<<dim3(NBLK), dim3(256), DYNLDS, stream>>>(
        Wth, Wtl, Xph, Xpl, bias, gih, bih, ghh, bhh, gc, bc, Hh, Hl, flags);

    final_kernel<<<B_, 256, 0, stream>>>(Hh, Hl, Wlin, blin, out);
}